// Round 4
// baseline (503.111 us; speedup 1.0000x reference)
//
#include <hip/hip_runtime.h>
#include <math.h>

// GCN 3-layer, bf16 features + MFMA GEMM (unfused: R8 fusion experiment regressed).
//   per layer: y = bf16(dinv * (H @ W)); h = relu(dinv*(A y + y) + b); final log-softmax.
// CSR built once per call via 2-phase LDS bucket sort (bucket = dst>>8).
// deg = indeg(dst) + 1 (self loop).
// R9:  relu-gather split into (node, channel-half) items keyed by blockIdx&1 (XCD parity).
// R11: src-CHUNKED gather (chunk = src>>14, 7 x 2MB half-row windows; persistent grid,
//   chunk loop outermost). Mechanism verified (true y-fetch ~114MB) but float a[4][8]
//   address-taken 2-D array defeated SROA -> 32 accs in scratch (WRITE 25->47MB, dur 2x).
// R12: spill fix — named 1-D accumulator arrays a0..a3[8] (R9-proven SROA shape) via
//   macro bodies; x2 inner unroll; launch_bounds(256,6) so no VGPR squeeze.

#define NN 100000
#define NE 1600000
#define NBUK 391          // ceil(100000/256)
#define BCAP 4608         // slots per bucket (mean 4096, sd 64 -> 8 sd headroom)
#define NCH 7             // src chunks: src>>14 -> 0..6 (16384 rows/chunk)

typedef float floatx4 __attribute__((ext_vector_type(4)));
typedef short short8 __attribute__((ext_vector_type(8)));

__device__ __forceinline__ unsigned short f2bf(float f) {
    unsigned u = __float_as_uint(f);
    unsigned r = (u + 0x7fffu + ((u >> 16) & 1u)) >> 16;   // RNE
    return (unsigned short)r;
}
__device__ __forceinline__ float bflo(unsigned u) { return __uint_as_float(u << 16); }
__device__ __forceinline__ float bfhi(unsigned u) { return __uint_as_float(u & 0xffff0000u); }

// ---------------- W prep (all 3): fp32 [K][NC] -> bf16 [NC][K] (transposed) ----------------
__global__ __launch_bounds__(256) void k_wprep_all(const float* __restrict__ W1, const float* __restrict__ W2,
                                                   const float* __restrict__ W3,
                                                   unsigned short* __restrict__ wt1, unsigned short* __restrict__ wt2,
                                                   unsigned short* __restrict__ wt3) {
    int idx = blockIdx.x * 256 + threadIdx.x;
    if (idx < 16384) {
        int n = idx >> 7, k = idx & 127;
        wt1[idx] = f2bf(W1[k * 128 + n]);
    } else if (idx < 32768) {
        int i = idx - 16384;
        int n = i >> 7, k = i & 127;
        wt2[i] = f2bf(W2[k * 128 + n]);
    } else if (idx < 40960) {
        int i = idx - 32768;
        int n = i >> 7, k = i & 127;       // wt3[n][k], n<64
        wt3[i] = f2bf(W3[k * 64 + n]);
    }
}

// ---------------- CSR build: phase A — bucketize (edges cached in registers across passes) ----------------
__global__ __launch_bounds__(256) void k_bucket(const int4* __restrict__ src4, const int4* __restrict__ dst4,
                                                int* __restrict__ bcur, int* __restrict__ bbuf, int E) {
    __shared__ int hist[NBUK];
    __shared__ int base[NBUK];
    int t = threadIdx.x;
    for (int b = t; b < NBUK; b += 256) hist[b] = 0;
    __syncthreads();
    int E4 = E >> 2;
    int q0 = blockIdx.x * 1024;
    int4 sv[4], dv[4];
    bool valid[4];
    #pragma unroll
    for (int j = 0; j < 4; j++) {
        int q = q0 + j * 256 + t;
        valid[j] = (q < E4);
        if (valid[j]) {
            sv[j] = src4[q];
            dv[j] = dst4[q];
            atomicAdd(&hist[dv[j].x >> 8], 1);
            atomicAdd(&hist[dv[j].y >> 8], 1);
            atomicAdd(&hist[dv[j].z >> 8], 1);
            atomicAdd(&hist[dv[j].w >> 8], 1);
        }
    }
    __syncthreads();
    for (int b = t; b < NBUK; b += 256) {
        int c = hist[b];
        base[b] = c ? atomicAdd(&bcur[b], c) : 0;
        hist[b] = 0;
    }
    __syncthreads();
    #pragma unroll
    for (int j = 0; j < 4; j++) {
        if (valid[j]) {
            int ss[4] = {sv[j].x, sv[j].y, sv[j].z, sv[j].w};
            int dd[4] = {dv[j].x, dv[j].y, dv[j].z, dv[j].w};
            #pragma unroll
            for (int u = 0; u < 4; u++) {
                int b = dd[u] >> 8;
                int r = atomicAdd(&hist[b], 1);
                int pos = base[b] + r;
                if (pos < BCAP) bbuf[b * BCAP + pos] = (ss[u] << 8) | (dd[u] & 255);
            }
        }
    }
}

// exclusive scan of bucket counts (single wave)
__global__ void k_scanbuckets(const int* __restrict__ bcur, int* __restrict__ bbase, int nb) {
    int lane = threadIdx.x;
    int carry = 0;
    for (int base = 0; base < nb; base += 64) {
        int idx = base + lane;
        int v = (idx < nb) ? min(bcur[idx], BCAP) : 0;
        int orig = v;
        #pragma unroll
        for (int o = 1; o < 64; o <<= 1) {
            int u = __shfl_up(v, o);
            if (lane >= o) v += u;
        }
        if (idx < nb) bbase[idx] = carry + v - orig;
        carry += __shfl(v, 63);
    }
}

// ---------------- CSR build: phase B — per-bucket counting sort in LDS (+ fused dinv) ----------------
// key = (dst&255)*8 | src_chunk  -> per-node lists sub-sorted by src chunk.
// rpc[node*8+c] = start of node's chunk-c segment; rpc[node*8+7] = end of node's list.
__global__ __launch_bounds__(256) void k_build(const int* __restrict__ bcur, const int* __restrict__ bbase,
                                               const int* __restrict__ bbuf,
                                               int* __restrict__ rpc, int* __restrict__ csr,
                                               float* __restrict__ dinv, int N) {
    __shared__ int sh[2048];
    __shared__ int cur[2048];
    __shared__ int tot[256];
    __shared__ int loc[BCAP];
    int b = blockIdx.x, t = threadIdx.x;
    int cnt = min(bcur[b], BCAP);
    int gbase = bbase[b];
    const int* bp = bbuf + b * BCAP;
    for (int k = t; k < 2048; k += 256) sh[k] = 0;
    __syncthreads();
    for (int i = t; i < cnt; i += 256) {
        int p = bp[i];
        // p = (src<<8)|dstlow, src<2^17  ->  chunk = src>>14 = (unsigned)p>>22 in [0,6]
        int key = ((p & 255) << 3) | (int)((unsigned)p >> 22);
        atomicAdd(&sh[key], 1);
    }
    __syncthreads();
    int run = 0;
    #pragma unroll
    for (int j = 0; j < 8; j++) run += sh[t * 8 + j];
    tot[t] = run;
    __syncthreads();
    for (int o = 1; o < 256; o <<= 1) {
        int u = (t >= o) ? tot[t - o] : 0;
        __syncthreads();
        tot[t] += u;
        __syncthreads();
    }
    int excl = tot[t] - run;       // start of this dst's list within bucket
    int node = b * 256 + t;
    int base = excl;
    #pragma unroll
    for (int j = 0; j < 8; j++) {  // j==7: sh[t*8+7]==0 always, so entry7 = excl+run = end
        if (node < N) rpc[node * 8 + j] = gbase + base;
        cur[t * 8 + j] = base;
        base += sh[t * 8 + j];
    }
    if (node < N) dinv[node] = rsqrtf((float)run + 1.0f);   // deg = indeg + 1 (self loop)
    __syncthreads();
    for (int i = t; i < cnt; i += 256) {
        int p = bp[i];
        int key = ((p & 255) << 3) | (int)((unsigned)p >> 22);
        int r = atomicAdd(&cur[key], 1);
        loc[r] = p >> 8;                       // src
    }
    __syncthreads();
    for (int i = t; i < cnt; i += 256) csr[gbase + i] = loc[i];
}

// ---------------- MFMA GEMM: Y[M,NC](bf16) = bf16( (A[M,128] @ W[128,NC]) * dinv[row] )

template <int NC, bool CVT>
__global__ __launch_bounds__(256) void k_mfma(const void* __restrict__ Av, const unsigned short* __restrict__ Wtg,
                                              const float* __restrict__ dinv, unsigned short* __restrict__ Y, int M) {
    constexpr int K = 128;
    constexpr int NT = NC / 16;
    constexpr int NU = NC / 32;
    __shared__ unsigned short Wt[NC][136];
    __shared__ unsigned short Ost[4][16][NC + 8];
    int t = threadIdx.x;
    for (int idx = t; idx < NC * 16; idx += 256) {
        int nrow = idx >> 4, chunk = idx & 15;
        *(uint4*)&Wt[nrow][chunk * 8] = *(const uint4*)(Wtg + nrow * K + chunk * 8);
    }
    __syncthreads();
    int lane = t & 63, wid = t >> 6;
    int col = lane & 15, quad = lane >> 4;
    int nstrips = M / 16;
    int stride = gridDim.x * 4;
    int s = blockIdx.x * 4 + wid;
    if (s >= nstrips) return;

    auto loadA = [&](int strip, short8 af[4]) {
        int row0 = strip * 16;
        if (CVT) {
            const float* Af = (const float*)Av + (size_t)(row0 + col) * K + quad * 8;
            #pragma unroll
            for (int ks = 0; ks < 4; ks++) {
                float4 f0 = *(const float4*)(Af + ks * 32);
                float4 f1 = *(const float4*)(Af + ks * 32 + 4);
                short8 v;
                v[0] = (short)f2bf(f0.x); v[1] = (short)f2bf(f0.y); v[2] = (short)f2bf(f0.z); v[3] = (short)f2bf(f0.w);
                v[4] = (short)f2bf(f1.x); v[5] = (short)f2bf(f1.y); v[6] = (short)f2bf(f1.z); v[7] = (short)f2bf(f1.w);
                af[ks] = v;
            }
        } else {
            const unsigned short* Ab = (const unsigned short*)Av + (size_t)(row0 + col) * K + quad * 8;
            #pragma unroll
            for (int ks = 0; ks < 4; ks++) af[ks] = *(const short8*)(Ab + ks * 32);
        }
    };

    short8 cur[4];
    loadA(s, cur);
    while (true) {
        int snext = s + stride;
        bool has = (snext < nstrips);
        short8 nxt[4];
        if (has) loadA(snext, nxt);

        floatx4 acc[NT];
        #pragma unroll
        for (int i = 0; i < NT; i++) acc[i] = (floatx4){0.f, 0.f, 0.f, 0.f};
        #pragma unroll
        for (int ks = 0; ks < 4; ks++) {
            #pragma unroll
            for (int nt = 0; nt < NT; nt++) {
                short8 bfrag = *(const short8*)&Wt[nt * 16 + col][ks * 32 + quad * 8];
                acc[nt] = __builtin_amdgcn_mfma_f32_16x16x32_bf16(cur[ks], bfrag, acc[nt], 0, 0, 0);
            }
        }
        int row0 = s * 16;
        #pragma unroll
        for (int r = 0; r < 4; r++) {
            float dv = dinv[row0 + quad * 4 + r];
            #pragma unroll
            for (int nt = 0; nt < NT; nt++)
                Ost[wid][quad * 4 + r][nt * 16 + col] = f2bf(acc[nt][r] * dv);
        }
        #pragma unroll
        for (int i = 0; i < NU; i++) {
            int idx = i * 64 + lane;
            int rr = (NC == 128) ? (idx >> 4) : (idx >> 3);
            int cc = (NC == 128) ? (idx & 15) : (idx & 7);
            ((uint4*)&Y[(size_t)(row0 + rr) * NC])[cc] = *(uint4*)&Ost[wid][rr][cc * 8];
        }
        if (!has) break;
        s = snext;
        #pragma unroll
        for (int ks = 0; ks < 4; ks++) cur[ks] = nxt[ks];
    }
}

// ---------------- gather + epilogue (bf16 rows), chunked persistent ----------------

__device__ __forceinline__ void acc8(float* a, uint4 v) {
    a[0] += bflo(v.x); a[1] += bfhi(v.x);
    a[2] += bflo(v.y); a[3] += bfhi(v.y);
    a[4] += bflo(v.z); a[5] += bfhi(v.z);
    a[6] += bflo(v.w); a[7] += bfhi(v.w);
}

// chunk-c segment of node NJ accumulated into named array A (R9-proven SROA shape)
#define GBODY16(A, NJ, SJ)                                                \
    if (NJ >= 0) {                                                        \
        int s1 = rpc[NJ * 8 + c + 1];                                     \
        if (c == (NJ >> 14)) acc8(A, y[(size_t)NJ * 16 + cidx]);          \
        int p = SJ;                                                       \
        for (; p + 2 <= s1; p += 2) {                                     \
            int i0 = csr[p], i1 = csr[p + 1];                             \
            uint4 v0 = y[(size_t)i0 * 16 + cidx];                         \
            uint4 v1 = y[(size_t)i1 * 16 + cidx];                         \
            acc8(A, v0); acc8(A, v1);                                     \
        }                                                                 \
        for (; p < s1; p++) acc8(A, y[(size_t)csr[p] * 16 + cidx]);       \
        SJ = s1;                                                          \
    }

#define GBODY8(A, NJ, SJ)                                                 \
    if (NJ >= 0) {                                                        \
        int s1 = rpc[NJ * 8 + c + 1];                                     \
        if (c == (NJ >> 14)) acc8(A, y[(size_t)NJ * 8 + cidx]);           \
        int p = SJ;                                                       \
        for (; p + 2 <= s1; p += 2) {                                     \
            int i0 = csr[p], i1 = csr[p + 1];                             \
            uint4 v0 = y[(size_t)i0 * 8 + cidx];                          \
            uint4 v1 = y[(size_t)i1 * 8 + cidx];                          \
            acc8(A, v0); acc8(A, v1);                                     \
        }                                                                 \
        for (; p < s1; p++) acc8(A, y[(size_t)csr[p] * 8 + cidx]);        \
        SJ = s1;                                                          \
    }

#define EPIRELU(A, NJ)                                                    \
    if (NJ >= 0) {                                                        \
        float s = dinv[NJ];                                               \
        float r0 = fmaxf(s * A[0] + b0.x, 0.f), r1 = fmaxf(s * A[1] + b0.y, 0.f); \
        float r2 = fmaxf(s * A[2] + b0.z, 0.f), r3 = fmaxf(s * A[3] + b0.w, 0.f); \
        float r4 = fmaxf(s * A[4] + b1.x, 0.f), r5 = fmaxf(s * A[5] + b1.y, 0.f); \
        float r6 = fmaxf(s * A[6] + b1.z, 0.f), r7 = fmaxf(s * A[7] + b1.w, 0.f); \
        uint4 o;                                                          \
        o.x = ((unsigned)f2bf(r1) << 16) | f2bf(r0);                      \
        o.y = ((unsigned)f2bf(r3) << 16) | f2bf(r2);                      \
        o.z = ((unsigned)f2bf(r5) << 16) | f2bf(r4);                      \
        o.w = ((unsigned)f2bf(r7) << 16) | f2bf(r6);                      \
        h[(size_t)NJ * 16 + cidx] = o;                                    \
    }

// 128 ch bf16. Persistent near-co-resident grid (1564 blocks; 1536 resident @6/CU).
// (item, channel-half); half = blockIdx&1 (XCD parity pinning -> 128B per row per XCD).
// Chunk loop OUTERMOST over 4 named register-accumulator groups: device-wide aligned
// 2MB src window per chunk phase -> L2 captures within-chunk reuse.
#define GRELU_GRID 1564   // even; per parity 782 * 32 items * 4 groups = 100096 >= N
__global__ __launch_bounds__(256, 6) void k_gather_relu_bf(const uint4* __restrict__ y, const int* __restrict__ csr,
                                                           const int* __restrict__ rpc,
                                                           const float* __restrict__ dinv,
                                                           const float* __restrict__ bias, uint4* __restrict__ h, int n) {
    int half = blockIdx.x & 1;
    int gh = blockIdx.x >> 1;               // 0..781
    int it = threadIdx.x >> 3;              // item 0..31
    int cidx = (threadIdx.x & 7) + half * 8;  // uint4 index within the 16-uint4 row
    int n0 = gh * 32 + it;
    int n1 = (gh + 782) * 32 + it;
    int n2 = (gh + 1564) * 32 + it;
    int n3 = (gh + 2346) * 32 + it;
    if (n0 >= n) n0 = -1;
    if (n1 >= n) n1 = -1;
    if (n2 >= n) n2 = -1;
    if (n3 >= n) n3 = -1;
    int s0 = (n0 >= 0) ? rpc[n0 * 8] : 0;
    int s1g = (n1 >= 0) ? rpc[n1 * 8] : 0;
    int s2 = (n2 >= 0) ? rpc[n2 * 8] : 0;
    int s3 = (n3 >= 0) ? rpc[n3 * 8] : 0;
    float a0[8] = {}, a1[8] = {}, a2[8] = {}, a3[8] = {};
    for (int c = 0; c < NCH; c++) {
        GBODY16(a0, n0, s0)
        GBODY16(a1, n1, s1g)
        GBODY16(a2, n2, s2)
        GBODY16(a3, n3, s3)
    }
    float4 b0 = ((const float4*)bias)[cidx * 2];
    float4 b1 = ((const float4*)bias)[cidx * 2 + 1];
    EPIRELU(a0, n0)
    EPIRELU(a1, n1)
    EPIRELU(a2, n2)
    EPIRELU(a3, n3)
}

#define EPILSM(A, NJ)                                                     \
    if (NJ >= 0) {                                                        \
        float s = dinv[NJ];                                               \
        float v[8];                                                       \
        v[0] = s * A[0] + b0.x; v[1] = s * A[1] + b0.y;                   \
        v[2] = s * A[2] + b0.z; v[3] = s * A[3] + b0.w;                   \
        v[4] = s * A[4] + b1.x; v[5] = s * A[5] + b1.y;                   \
        v[6] = s * A[6] + b1.z; v[7] = s * A[7] + b1.w;                   \
        float m = v[0];                                                   \
        _Pragma("unroll")                                                 \
        for (int i = 1; i < 8; i++) m = fmaxf(m, v[i]);                   \
        _Pragma("unroll")                                                 \
        for (int o = 4; o > 0; o >>= 1) m = fmaxf(m, __shfl_xor(m, o));   \
        float sum = 0.f;                                                  \
        _Pragma("unroll")                                                 \
        for (int i = 0; i < 8; i++) sum += expf(v[i] - m);                \
        _Pragma("unroll")                                                 \
        for (int o = 4; o > 0; o >>= 1) sum += __shfl_xor(sum, o);        \
        float lse = m + logf(sum);                                        \
        out4[(size_t)NJ * 16 + cidx * 2]     = make_float4(v[0] - lse, v[1] - lse, v[2] - lse, v[3] - lse); \
        out4[(size_t)NJ * 16 + cidx * 2 + 1] = make_float4(v[4] - lse, v[5] - lse, v[6] - lse, v[7] - lse); \
    }

// 64 ch bf16 + log-softmax: persistent chunked, 8 threads/node, 2 named groups, fp32 out.
#define GLSM_GRID 1564    // 1564 * 32 items * 2 groups = 100096 >= N
__global__ __launch_bounds__(256, 6) void k_gather_lsm_bf(const uint4* __restrict__ y, const int* __restrict__ csr,
                                                          const int* __restrict__ rpc,
                                                          const float* __restrict__ dinv,
                                                          const float* __restrict__ bias, float4* __restrict__ out4, int n) {
    int it = threadIdx.x >> 3;
    int cidx = threadIdx.x & 7;
    int n0 = blockIdx.x * 32 + it;
    int n1 = (blockIdx.x + GLSM_GRID) * 32 + it;
    if (n0 >= n) n0 = -1;
    if (n1 >= n) n1 = -1;
    int s0 = (n0 >= 0) ? rpc[n0 * 8] : 0;
    int s1g = (n1 >= 0) ? rpc[n1 * 8] : 0;
    float a0[8] = {}, a1[8] = {};
    for (int c = 0; c < NCH; c++) {
        GBODY8(a0, n0, s0)
        GBODY8(a1, n1, s1g)
    }
    float4 b0 = ((const float4*)bias)[cidx * 2];
    float4 b1 = ((const float4*)bias)[cidx * 2 + 1];
    EPILSM(a0, n0)
    EPILSM(a1, n1)
}

// ---------------- launch ----------------

extern "C" void kernel_launch(void* const* d_in, const int* in_sizes, int n_in,
                              void* d_out, int out_size, void* d_ws, size_t ws_size,
                              hipStream_t stream) {
    const float* x  = (const float*)d_in[0];
    const int*   ei = (const int*)d_in[1];
    const float* W1 = (const float*)d_in[2];
    const float* b1 = (const float*)d_in[3];
    const float* W2 = (const float*)d_in[4];
    const float* b2 = (const float*)d_in[5];
    const float* W3 = (const float*)d_in[6];
    const float* b3 = (const float*)d_in[7];
    float* out = (float*)d_out;

    const int N = NN, E = NE;

    char* ws = (char*)d_ws;
    size_t off = 0;
    auto alloc = [&](size_t bytes) -> void* {
        void* p = ws + off;
        off += bytes;
        off = (off + 255) & ~(size_t)255;
        return p;
    };
    int*            rpc     = (int*)alloc((size_t)(N * 8 + 8) * 4);
    float*          dinvv   = (float*)alloc((size_t)N * 4);
    int*            bcur    = (int*)alloc(512 * 4);
    int*            bbase   = (int*)alloc(512 * 4);
    int*            bbuf    = (int*)alloc((size_t)NBUK * BCAP * 4);
    int*            csr     = (int*)alloc((size_t)E * 4);
    unsigned short* wt1     = (unsigned short*)alloc(128 * 128 * 2);
    unsigned short* wt2     = (unsigned short*)alloc(128 * 128 * 2);
    unsigned short* wt3     = (unsigned short*)alloc(64 * 128 * 2);
    unsigned short* yb      = (unsigned short*)alloc((size_t)N * 128 * 2);
    unsigned short* hb      = (unsigned short*)alloc((size_t)N * 128 * 2);
    (void)ws_size; (void)in_sizes; (void)n_in; (void)out_size;

    const int* srcp = ei;
    const int* dstp = ei + E;

    hipMemsetAsync(bcur, 0, 512 * 4, stream);
    k_wprep_all<<<160, 256, 0, stream>>>(W1, W2, W3, wt1, wt2, wt3);
    k_bucket<<<(E + 4095) / 4096, 256, 0, stream>>>((const int4*)srcp, (const int4*)dstp, bcur, bbuf, E);
    k_scanbuckets<<<1, 64, 0, stream>>>(bcur, bbase, NBUK);
    k_build<<<NBUK, 256, 0, stream>>>(bcur, bbase, bbuf, rpc, csr, dinvv, N);

    // Layer 1 (fp32 x converted in-register)
    k_mfma<128, true><<<768, 256, 0, stream>>>(x, wt1, dinvv, yb, N);
    k_gather_relu_bf<<<GRELU_GRID, 256, 0, stream>>>((const uint4*)yb, csr, rpc, dinvv, b1, (uint4*)hb, N);
    // Layer 2
    k_mfma<128, false><<<768, 256, 0, stream>>>(hb, wt2, dinvv, yb, N);
    k_gather_relu_bf<<<GRELU_GRID, 256, 0, stream>>>((const uint4*)yb, csr, rpc, dinvv, b2, (uint4*)hb, N);
    // Layer 3 (128 -> 64) + log-softmax
    k_mfma<64, false><<<768, 256, 0, stream>>>(hb, wt3, dinvv, yb, N);
    k_gather_lsm_bf<<<GLSM_GRID, 256, 0, stream>>>((const uint4*)yb, csr, rpc, dinvv, b3, (float4*)out, N);
}

// Round 5
// 326.188 us; speedup vs baseline: 1.5424x; 1.5424x over previous
//
#include <hip/hip_runtime.h>
#include <math.h>

// GCN 3-layer, bf16 features + MFMA GEMM (unfused: R8 fusion experiment regressed).
//   per layer: y = bf16(dinv * (H @ W)); h = relu(dinv*(A y + y) + b); final log-softmax.
// CSR built once per call via 2-phase LDS bucket sort (bucket = dst>>8).
// deg = indeg(dst) + 1 (self loop).
// R9: relu-gather split into (node, channel-half) items keyed by blockIdx&1 (XCD parity).
//   HW round-robins blocks over XCDs (blk%8), so each XCD's L2 mostly fetches ONE
//   128B half-line of each y row: FETCH 189->168MB, gather 60.7->57.3us.
// R10-R12: degree-sort and src-chunked-window experiments — REVERTED. Chunking cut true
//   y-fetch to ~114MB (mechanism verified) but fragmented per-wave MLP (7 short segments
//   + rpc deps) and pushed accumulator state to scratch: latency-bound at 1.3-1.65 TB/s,
//   2-2.5x slower despite fewer bytes. Gather here = 3.4 TB/s ~ random-row LLC ceiling.

#define NN 100000
#define NE 1600000
#define NBUK 391          // ceil(100000/256)
#define BCAP 4608         // slots per bucket (mean 4096, sd 64 -> 8 sd headroom)

typedef float floatx4 __attribute__((ext_vector_type(4)));
typedef short short8 __attribute__((ext_vector_type(8)));

__device__ __forceinline__ unsigned short f2bf(float f) {
    unsigned u = __float_as_uint(f);
    unsigned r = (u + 0x7fffu + ((u >> 16) & 1u)) >> 16;   // RNE
    return (unsigned short)r;
}
__device__ __forceinline__ float bflo(unsigned u) { return __uint_as_float(u << 16); }
__device__ __forceinline__ float bfhi(unsigned u) { return __uint_as_float(u & 0xffff0000u); }

// ---------------- W prep (all 3): fp32 [K][NC] -> bf16 [NC][K] (transposed) ----------------
__global__ __launch_bounds__(256) void k_wprep_all(const float* __restrict__ W1, const float* __restrict__ W2,
                                                   const float* __restrict__ W3,
                                                   unsigned short* __restrict__ wt1, unsigned short* __restrict__ wt2,
                                                   unsigned short* __restrict__ wt3) {
    int idx = blockIdx.x * 256 + threadIdx.x;
    if (idx < 16384) {
        int n = idx >> 7, k = idx & 127;
        wt1[idx] = f2bf(W1[k * 128 + n]);
    } else if (idx < 32768) {
        int i = idx - 16384;
        int n = i >> 7, k = i & 127;
        wt2[i] = f2bf(W2[k * 128 + n]);
    } else if (idx < 40960) {
        int i = idx - 32768;
        int n = i >> 7, k = i & 127;       // wt3[n][k], n<64
        wt3[i] = f2bf(W3[k * 64 + n]);
    }
}

// ---------------- CSR build: phase A — bucketize (edges cached in registers across passes) ----------------
__global__ __launch_bounds__(256) void k_bucket(const int4* __restrict__ src4, const int4* __restrict__ dst4,
                                                int* __restrict__ bcur, int* __restrict__ bbuf, int E) {
    __shared__ int hist[NBUK];
    __shared__ int base[NBUK];
    int t = threadIdx.x;
    for (int b = t; b < NBUK; b += 256) hist[b] = 0;
    __syncthreads();
    int E4 = E >> 2;
    int q0 = blockIdx.x * 1024;
    int4 sv[4], dv[4];
    bool valid[4];
    #pragma unroll
    for (int j = 0; j < 4; j++) {
        int q = q0 + j * 256 + t;
        valid[j] = (q < E4);
        if (valid[j]) {
            sv[j] = src4[q];
            dv[j] = dst4[q];
            atomicAdd(&hist[dv[j].x >> 8], 1);
            atomicAdd(&hist[dv[j].y >> 8], 1);
            atomicAdd(&hist[dv[j].z >> 8], 1);
            atomicAdd(&hist[dv[j].w >> 8], 1);
        }
    }
    __syncthreads();
    for (int b = t; b < NBUK; b += 256) {
        int c = hist[b];
        base[b] = c ? atomicAdd(&bcur[b], c) : 0;
        hist[b] = 0;
    }
    __syncthreads();
    #pragma unroll
    for (int j = 0; j < 4; j++) {
        if (valid[j]) {
            int ss[4] = {sv[j].x, sv[j].y, sv[j].z, sv[j].w};
            int dd[4] = {dv[j].x, dv[j].y, dv[j].z, dv[j].w};
            #pragma unroll
            for (int u = 0; u < 4; u++) {
                int b = dd[u] >> 8;
                int r = atomicAdd(&hist[b], 1);
                int pos = base[b] + r;
                if (pos < BCAP) bbuf[b * BCAP + pos] = (ss[u] << 8) | (dd[u] & 255);
            }
        }
    }
}

// exclusive scan of bucket counts (single wave), also row_ptr[N] = E
__global__ void k_scanbuckets(const int* __restrict__ bcur, int* __restrict__ bbase, int nb,
                              int* __restrict__ row_ptr, int n, int E) {
    int lane = threadIdx.x;
    int carry = 0;
    for (int base = 0; base < nb; base += 64) {
        int idx = base + lane;
        int v = (idx < nb) ? min(bcur[idx], BCAP) : 0;
        int orig = v;
        #pragma unroll
        for (int o = 1; o < 64; o <<= 1) {
            int u = __shfl_up(v, o);
            if (lane >= o) v += u;
        }
        if (idx < nb) bbase[idx] = carry + v - orig;
        carry += __shfl(v, 63);
    }
    if (lane == 0) row_ptr[n] = E;
}

// ---------------- CSR build: phase B — per-bucket counting sort in LDS (+ fused dinv) ----------------
__global__ __launch_bounds__(256) void k_build(const int* __restrict__ bcur, const int* __restrict__ bbase,
                                               const int* __restrict__ bbuf,
                                               int* __restrict__ row_ptr, int* __restrict__ csr,
                                               float* __restrict__ dinv, int N) {
    __shared__ int sh[256];
    __shared__ int cur[256];
    __shared__ int loc[BCAP];
    int b = blockIdx.x, t = threadIdx.x;
    int cnt = min(bcur[b], BCAP);
    int gbase = bbase[b];
    const int* bp = bbuf + b * BCAP;
    sh[t] = 0;
    __syncthreads();
    for (int i = t; i < cnt; i += 256) atomicAdd(&sh[bp[i] & 255], 1);
    __syncthreads();
    int v = sh[t];
    for (int o = 1; o < 256; o <<= 1) {
        int u = (t >= o) ? sh[t - o] : 0;
        __syncthreads();
        sh[t] += u;
        __syncthreads();
    }
    int excl = sh[t] - v;
    int node = b * 256 + t;
    if (node < N) {
        row_ptr[node] = gbase + excl;
        dinv[node] = rsqrtf((float)v + 1.0f);   // deg = indeg + 1 (self loop)
    }
    cur[t] = excl;
    __syncthreads();
    for (int i = t; i < cnt; i += 256) {
        int p = bp[i];
        int r = atomicAdd(&cur[p & 255], 1);
        loc[r] = p >> 8;                       // src
    }
    __syncthreads();
    for (int i = t; i < cnt; i += 256) csr[gbase + i] = loc[i];
}

// ---------------- MFMA GEMM: Y[M,NC](bf16) = bf16( (A[M,128] @ W[128,NC]) * dinv[row] )
// Persistent: each wave loops strips with register double-buffer prefetch.
// Wtg pre-transposed bf16 [NC][K]; staged into LDS once per block.
// Epilogue staged through per-wave LDS tile -> coalesced uint4 stores.
// Layouts (16x16x32 bf16): A: lane holds A[m=lane&15][k=quad*8+j]; B: lane holds B[k=quad*8+j][n=lane&15];
// C/D: col=lane&15, row=quad*4+reg.

template <int NC, bool CVT>
__global__ __launch_bounds__(256) void k_mfma(const void* __restrict__ Av, const unsigned short* __restrict__ Wtg,
                                              const float* __restrict__ dinv, unsigned short* __restrict__ Y, int M) {
    constexpr int K = 128;
    constexpr int NT = NC / 16;
    constexpr int NU = NC / 32;
    __shared__ unsigned short Wt[NC][136];
    __shared__ unsigned short Ost[4][16][NC + 8];
    int t = threadIdx.x;
    for (int idx = t; idx < NC * 16; idx += 256) {
        int nrow = idx >> 4, chunk = idx & 15;
        *(uint4*)&Wt[nrow][chunk * 8] = *(const uint4*)(Wtg + nrow * K + chunk * 8);
    }
    __syncthreads();
    int lane = t & 63, wid = t >> 6;
    int col = lane & 15, quad = lane >> 4;
    int nstrips = M / 16;
    int stride = gridDim.x * 4;
    int s = blockIdx.x * 4 + wid;
    if (s >= nstrips) return;

    auto loadA = [&](int strip, short8 af[4]) {
        int row0 = strip * 16;
        if (CVT) {
            const float* Af = (const float*)Av + (size_t)(row0 + col) * K + quad * 8;
            #pragma unroll
            for (int ks = 0; ks < 4; ks++) {
                float4 f0 = *(const float4*)(Af + ks * 32);
                float4 f1 = *(const float4*)(Af + ks * 32 + 4);
                short8 v;
                v[0] = (short)f2bf(f0.x); v[1] = (short)f2bf(f0.y); v[2] = (short)f2bf(f0.z); v[3] = (short)f2bf(f0.w);
                v[4] = (short)f2bf(f1.x); v[5] = (short)f2bf(f1.y); v[6] = (short)f2bf(f1.z); v[7] = (short)f2bf(f1.w);
                af[ks] = v;
            }
        } else {
            const unsigned short* Ab = (const unsigned short*)Av + (size_t)(row0 + col) * K + quad * 8;
            #pragma unroll
            for (int ks = 0; ks < 4; ks++) af[ks] = *(const short8*)(Ab + ks * 32);
        }
    };

    short8 cur[4];
    loadA(s, cur);
    while (true) {
        int snext = s + stride;
        bool has = (snext < nstrips);
        short8 nxt[4];
        if (has) loadA(snext, nxt);

        floatx4 acc[NT];
        #pragma unroll
        for (int i = 0; i < NT; i++) acc[i] = (floatx4){0.f, 0.f, 0.f, 0.f};
        #pragma unroll
        for (int ks = 0; ks < 4; ks++) {
            #pragma unroll
            for (int nt = 0; nt < NT; nt++) {
                short8 bfrag = *(const short8*)&Wt[nt * 16 + col][ks * 32 + quad * 8];
                acc[nt] = __builtin_amdgcn_mfma_f32_16x16x32_bf16(cur[ks], bfrag, acc[nt], 0, 0, 0);
            }
        }
        int row0 = s * 16;
        #pragma unroll
        for (int r = 0; r < 4; r++) {
            float dv = dinv[row0 + quad * 4 + r];
            #pragma unroll
            for (int nt = 0; nt < NT; nt++)
                Ost[wid][quad * 4 + r][nt * 16 + col] = f2bf(acc[nt][r] * dv);
        }
        #pragma unroll
        for (int i = 0; i < NU; i++) {
            int idx = i * 64 + lane;
            int rr = (NC == 128) ? (idx >> 4) : (idx >> 3);
            int cc = (NC == 128) ? (idx & 15) : (idx & 7);
            ((uint4*)&Y[(size_t)(row0 + rr) * NC])[cc] = *(uint4*)&Ost[wid][rr][cc * 8];
        }
        if (!has) break;
        s = snext;
        #pragma unroll
        for (int ks = 0; ks < 4; ks++) cur[ks] = nxt[ks];
    }
}

// ---------------- gather + epilogue (bf16 rows), x4 unroll ----------------

__device__ __forceinline__ void acc8(float* a, uint4 v) {
    a[0] += bflo(v.x); a[1] += bfhi(v.x);
    a[2] += bflo(v.y); a[3] += bfhi(v.y);
    a[4] += bflo(v.z); a[5] += bfhi(v.z);
    a[6] += bflo(v.w); a[7] += bfhi(v.w);
}

// 128 ch bf16, split by channel-half (one 128B L2 line per half):
// work item = (node, half); half = blockIdx&1 so HW's blk%8 XCD round-robin pins
// each half to a fixed XCD parity class -> per-XCD L2 only fetches half of each row.
// 8 threads/item, 8 ch (one uint4) per thread, 32 items/block.
__global__ __launch_bounds__(256) void k_gather_relu_bf(const uint4* __restrict__ y, const int* __restrict__ csr,
                                                        const int* __restrict__ row_ptr, const float* __restrict__ dinv,
                                                        const float* __restrict__ bias, uint4* __restrict__ h, int n) {
    int half = blockIdx.x & 1;
    int node = (blockIdx.x >> 1) * 32 + (threadIdx.x >> 3);
    int c = (threadIdx.x & 7) + half * 8;   // uint4 index within the 16-uint4 row
    if (node >= n) return;
    int s0 = row_ptr[node], s1 = row_ptr[node + 1];
    float a[8] = {};
    acc8(a, y[(size_t)node * 16 + c]);       // self loop
    int p = s0;
    for (; p + 4 <= s1; p += 4) {
        int i0 = csr[p], i1 = csr[p + 1], i2 = csr[p + 2], i3 = csr[p + 3];
        uint4 v0 = y[(size_t)i0 * 16 + c];
        uint4 v1 = y[(size_t)i1 * 16 + c];
        uint4 v2 = y[(size_t)i2 * 16 + c];
        uint4 v3 = y[(size_t)i3 * 16 + c];
        acc8(a, v0); acc8(a, v1); acc8(a, v2); acc8(a, v3);
    }
    for (; p < s1; p++) acc8(a, y[(size_t)csr[p] * 16 + c]);
    float s = dinv[node];
    float4 b0 = ((const float4*)bias)[c * 2];
    float4 b1 = ((const float4*)bias)[c * 2 + 1];
    float r0 = fmaxf(s * a[0] + b0.x, 0.f), r1 = fmaxf(s * a[1] + b0.y, 0.f);
    float r2 = fmaxf(s * a[2] + b0.z, 0.f), r3 = fmaxf(s * a[3] + b0.w, 0.f);
    float r4 = fmaxf(s * a[4] + b1.x, 0.f), r5 = fmaxf(s * a[5] + b1.y, 0.f);
    float r6 = fmaxf(s * a[6] + b1.z, 0.f), r7 = fmaxf(s * a[7] + b1.w, 0.f);
    uint4 o;
    o.x = ((unsigned)f2bf(r1) << 16) | f2bf(r0);
    o.y = ((unsigned)f2bf(r3) << 16) | f2bf(r2);
    o.z = ((unsigned)f2bf(r5) << 16) | f2bf(r4);
    o.w = ((unsigned)f2bf(r7) << 16) | f2bf(r6);
    h[(size_t)node * 16 + c] = o;
}

// 64 ch bf16 + log-softmax: 8 threads/node, 8 ch per thread, 32 nodes/block. fp32 output.
// (no channel split: log-softmax needs the full row reduction, and 128B row = 1 line already)
__global__ __launch_bounds__(256) void k_gather_lsm_bf(const uint4* __restrict__ y, const int* __restrict__ csr,
                                                       const int* __restrict__ row_ptr, const float* __restrict__ dinv,
                                                       const float* __restrict__ bias, float4* __restrict__ out4, int n) {
    int node = blockIdx.x * 32 + (threadIdx.x >> 3);
    int c = threadIdx.x & 7;
    if (node >= n) return;
    int s0 = row_ptr[node], s1 = row_ptr[node + 1];
    float a[8] = {};
    acc8(a, y[(size_t)node * 8 + c]);
    int p = s0;
    for (; p + 4 <= s1; p += 4) {
        int i0 = csr[p], i1 = csr[p + 1], i2 = csr[p + 2], i3 = csr[p + 3];
        uint4 v0 = y[(size_t)i0 * 8 + c];
        uint4 v1 = y[(size_t)i1 * 8 + c];
        uint4 v2 = y[(size_t)i2 * 8 + c];
        uint4 v3 = y[(size_t)i3 * 8 + c];
        acc8(a, v0); acc8(a, v1); acc8(a, v2); acc8(a, v3);
    }
    for (; p < s1; p++) acc8(a, y[(size_t)csr[p] * 8 + c]);
    float s = dinv[node];
    float4 b0 = ((const float4*)bias)[c * 2];
    float4 b1 = ((const float4*)bias)[c * 2 + 1];
    float v[8];
    v[0] = s * a[0] + b0.x; v[1] = s * a[1] + b0.y; v[2] = s * a[2] + b0.z; v[3] = s * a[3] + b0.w;
    v[4] = s * a[4] + b1.x; v[5] = s * a[5] + b1.y; v[6] = s * a[6] + b1.z; v[7] = s * a[7] + b1.w;
    float m = v[0];
    #pragma unroll
    for (int i = 1; i < 8; i++) m = fmaxf(m, v[i]);
    #pragma unroll
    for (int o = 4; o > 0; o >>= 1) m = fmaxf(m, __shfl_xor(m, o));
    float sum = 0.f;
    #pragma unroll
    for (int i = 0; i < 8; i++) sum += expf(v[i] - m);
    #pragma unroll
    for (int o = 4; o > 0; o >>= 1) sum += __shfl_xor(sum, o);
    float lse = m + logf(sum);
    out4[(size_t)node * 16 + c * 2]     = make_float4(v[0] - lse, v[1] - lse, v[2] - lse, v[3] - lse);
    out4[(size_t)node * 16 + c * 2 + 1] = make_float4(v[4] - lse, v[5] - lse, v[6] - lse, v[7] - lse);
}

// ---------------- launch ----------------

extern "C" void kernel_launch(void* const* d_in, const int* in_sizes, int n_in,
                              void* d_out, int out_size, void* d_ws, size_t ws_size,
                              hipStream_t stream) {
    const float* x  = (const float*)d_in[0];
    const int*   ei = (const int*)d_in[1];
    const float* W1 = (const float*)d_in[2];
    const float* b1 = (const float*)d_in[3];
    const float* W2 = (const float*)d_in[4];
    const float* b2 = (const float*)d_in[5];
    const float* W3 = (const float*)d_in[6];
    const float* b3 = (const float*)d_in[7];
    float* out = (float*)d_out;

    const int N = NN, E = NE;

    char* ws = (char*)d_ws;
    size_t off = 0;
    auto alloc = [&](size_t bytes) -> void* {
        void* p = ws + off;
        off += bytes;
        off = (off + 255) & ~(size_t)255;
        return p;
    };
    int*            row_ptr = (int*)alloc((size_t)(N + 1) * 4);
    float*          dinvv   = (float*)alloc((size_t)N * 4);
    int*            bcur    = (int*)alloc(512 * 4);
    int*            bbase   = (int*)alloc(512 * 4);
    int*            bbuf    = (int*)alloc((size_t)NBUK * BCAP * 4);
    int*            csr     = (int*)alloc((size_t)E * 4);
    unsigned short* wt1     = (unsigned short*)alloc(128 * 128 * 2);
    unsigned short* wt2     = (unsigned short*)alloc(128 * 128 * 2);
    unsigned short* wt3     = (unsigned short*)alloc(64 * 128 * 2);
    unsigned short* yb      = (unsigned short*)alloc((size_t)N * 128 * 2);
    unsigned short* hb      = (unsigned short*)alloc((size_t)N * 128 * 2);
    (void)ws_size; (void)in_sizes; (void)n_in; (void)out_size;

    const int* srcp = ei;
    const int* dstp = ei + E;

    hipMemsetAsync(bcur, 0, 512 * 4, stream);
    k_wprep_all<<<160, 256, 0, stream>>>(W1, W2, W3, wt1, wt2, wt3);
    k_bucket<<<(E + 4095) / 4096, 256, 0, stream>>>((const int4*)srcp, (const int4*)dstp, bcur, bbuf, E);
    k_scanbuckets<<<1, 64, 0, stream>>>(bcur, bbase, NBUK, row_ptr, N, E);
    k_build<<<NBUK, 256, 0, stream>>>(bcur, bbase, bbuf, row_ptr, csr, dinvv, N);

    // Layer 1 (fp32 x converted in-register)
    k_mfma<128, true><<<768, 256, 0, stream>>>(x, wt1, dinvv, yb, N);
    k_gather_relu_bf<<<(N / 32) * 2, 256, 0, stream>>>((const uint4*)yb, csr, row_ptr, dinvv, b1, (uint4*)hb, N);
    // Layer 2
    k_mfma<128, false><<<768, 256, 0, stream>>>(hb, wt2, dinvv, yb, N);
    k_gather_relu_bf<<<(N / 32) * 2, 256, 0, stream>>>((const uint4*)yb, csr, row_ptr, dinvv, b2, (uint4*)hb, N);
    // Layer 3 (128 -> 64) + log-softmax
    k_mfma<64, false><<<768, 256, 0, stream>>>(hb, wt3, dinvv, yb, N);
    k_gather_lsm_bf<<<N / 32, 256, 0, stream>>>((const uint4*)yb, csr, row_ptr, dinvv, b3, (float4*)out, N);
}

// Round 6
// 319.186 us; speedup vs baseline: 1.5762x; 1.0219x over previous
//
#include <hip/hip_runtime.h>
#include <math.h>

// GCN 3-layer, bf16 features + MFMA GEMM (unfused: R8 fusion experiment regressed).
//   per layer: y = bf16(dinv * (H @ W)); h = relu(dinv*(A y + y) + b); final log-softmax.
// CSR built once per call via 2-phase LDS bucket sort (bucket = dst>>8).
// deg = indeg(dst) + 1 (self loop).
// R9: relu-gather split into (node, channel-half) items keyed by blockIdx&1 (XCD parity).
//   FETCH 189->168MB, gather 60.7->57.3us = 3.4 TB/s ~ 95% of random-row LLC ceiling.
// R10-R12: degree-sort and src-chunked-window experiments — REVERTED. Chunking cut true
//   y-fetch to ~114MB (verified) but fragmented per-wave MLP and spilled accumulators:
//   latency-bound at 1.3-1.65 TB/s despite fewer bytes. Byte-reduction is anti-productive here.
// R13: dispatch-chain compression. memset folded into wprep (block 0 zeroes bcur);
//   bucket-scan folded into k_build (per-block redundant prefix over 391 bcur entries);
//   row_ptr[N] written by last build block. 11 dispatches -> 9.

#define NN 100000
#define NE 1600000
#define NBUK 391          // ceil(100000/256)
#define BCAP 4608         // slots per bucket (mean 4096, sd 64 -> 8 sd headroom)

typedef float floatx4 __attribute__((ext_vector_type(4)));
typedef short short8 __attribute__((ext_vector_type(8)));

__device__ __forceinline__ unsigned short f2bf(float f) {
    unsigned u = __float_as_uint(f);
    unsigned r = (u + 0x7fffu + ((u >> 16) & 1u)) >> 16;   // RNE
    return (unsigned short)r;
}
__device__ __forceinline__ float bflo(unsigned u) { return __uint_as_float(u << 16); }
__device__ __forceinline__ float bfhi(unsigned u) { return __uint_as_float(u & 0xffff0000u); }

// ---------------- W prep (all 3): fp32 [K][NC] -> bf16 [NC][K] (transposed); also zero bcur ----------------
__global__ __launch_bounds__(256) void k_wprep_all(const float* __restrict__ W1, const float* __restrict__ W2,
                                                   const float* __restrict__ W3,
                                                   unsigned short* __restrict__ wt1, unsigned short* __restrict__ wt2,
                                                   unsigned short* __restrict__ wt3, int* __restrict__ bcur) {
    if (blockIdx.x == 0) {
        bcur[threadIdx.x] = 0;
        bcur[threadIdx.x + 256] = 0;
    }
    int idx = blockIdx.x * 256 + threadIdx.x;
    if (idx < 16384) {
        int n = idx >> 7, k = idx & 127;
        wt1[idx] = f2bf(W1[k * 128 + n]);
    } else if (idx < 32768) {
        int i = idx - 16384;
        int n = i >> 7, k = i & 127;
        wt2[i] = f2bf(W2[k * 128 + n]);
    } else if (idx < 40960) {
        int i = idx - 32768;
        int n = i >> 7, k = i & 127;       // wt3[n][k], n<64
        wt3[i] = f2bf(W3[k * 64 + n]);
    }
}

// ---------------- CSR build: phase A — bucketize (edges cached in registers across passes) ----------------
__global__ __launch_bounds__(256) void k_bucket(const int4* __restrict__ src4, const int4* __restrict__ dst4,
                                                int* __restrict__ bcur, int* __restrict__ bbuf, int E) {
    __shared__ int hist[NBUK];
    __shared__ int base[NBUK];
    int t = threadIdx.x;
    for (int b = t; b < NBUK; b += 256) hist[b] = 0;
    __syncthreads();
    int E4 = E >> 2;
    int q0 = blockIdx.x * 1024;
    int4 sv[4], dv[4];
    bool valid[4];
    #pragma unroll
    for (int j = 0; j < 4; j++) {
        int q = q0 + j * 256 + t;
        valid[j] = (q < E4);
        if (valid[j]) {
            sv[j] = src4[q];
            dv[j] = dst4[q];
            atomicAdd(&hist[dv[j].x >> 8], 1);
            atomicAdd(&hist[dv[j].y >> 8], 1);
            atomicAdd(&hist[dv[j].z >> 8], 1);
            atomicAdd(&hist[dv[j].w >> 8], 1);
        }
    }
    __syncthreads();
    for (int b = t; b < NBUK; b += 256) {
        int c = hist[b];
        base[b] = c ? atomicAdd(&bcur[b], c) : 0;
        hist[b] = 0;
    }
    __syncthreads();
    #pragma unroll
    for (int j = 0; j < 4; j++) {
        if (valid[j]) {
            int ss[4] = {sv[j].x, sv[j].y, sv[j].z, sv[j].w};
            int dd[4] = {dv[j].x, dv[j].y, dv[j].z, dv[j].w};
            #pragma unroll
            for (int u = 0; u < 4; u++) {
                int b = dd[u] >> 8;
                int r = atomicAdd(&hist[b], 1);
                int pos = base[b] + r;
                if (pos < BCAP) bbuf[b * BCAP + pos] = (ss[u] << 8) | (dd[u] & 255);
            }
        }
    }
}

// ---------------- CSR build: phase B — per-bucket counting sort in LDS (+ fused dinv + fused scan) ----------------
__global__ __launch_bounds__(256) void k_build(const int* __restrict__ bcur, const int* __restrict__ bbuf,
                                               int* __restrict__ row_ptr, int* __restrict__ csr,
                                               float* __restrict__ dinv, int N, int E) {
    __shared__ int sh[256];
    __shared__ int cur[256];
    __shared__ int red[256];
    __shared__ int loc[BCAP];
    int b = blockIdx.x, t = threadIdx.x;
    int cnt = min(bcur[b], BCAP);
    // fused exclusive scan: gbase = sum_{j<b} min(bcur[j], BCAP)  (<=2 entries/thread + tree reduce)
    int partial = 0;
    for (int j = t; j < b; j += 256) partial += min(bcur[j], BCAP);
    red[t] = partial;
    sh[t] = 0;
    __syncthreads();
    #pragma unroll
    for (int o = 128; o > 0; o >>= 1) {
        if (t < o) red[t] += red[t + o];
        __syncthreads();
    }
    int gbase = red[0];
    const int* bp = bbuf + b * BCAP;
    for (int i = t; i < cnt; i += 256) atomicAdd(&sh[bp[i] & 255], 1);
    __syncthreads();
    int v = sh[t];
    for (int o = 1; o < 256; o <<= 1) {
        int u = (t >= o) ? sh[t - o] : 0;
        __syncthreads();
        sh[t] += u;
        __syncthreads();
    }
    int excl = sh[t] - v;
    int node = b * 256 + t;
    if (node < N) {
        row_ptr[node] = gbase + excl;
        dinv[node] = rsqrtf((float)v + 1.0f);   // deg = indeg + 1 (self loop)
    }
    if (b == NBUK - 1 && t == 0) row_ptr[N] = gbase + cnt;   // == E unless (8-sigma) clamp
    cur[t] = excl;
    __syncthreads();
    for (int i = t; i < cnt; i += 256) {
        int p = bp[i];
        int r = atomicAdd(&cur[p & 255], 1);
        loc[r] = p >> 8;                       // src
    }
    __syncthreads();
    for (int i = t; i < cnt; i += 256) csr[gbase + i] = loc[i];
}

// ---------------- MFMA GEMM: Y[M,NC](bf16) = bf16( (A[M,128] @ W[128,NC]) * dinv[row] )
// Persistent: each wave loops strips with register double-buffer prefetch.
// Wtg pre-transposed bf16 [NC][K]; staged into LDS once per block.
// Epilogue staged through per-wave LDS tile -> coalesced uint4 stores.
// Layouts (16x16x32 bf16): A: lane holds A[m=lane&15][k=quad*8+j]; B: lane holds B[k=quad*8+j][n=lane&15];
// C/D: col=lane&15, row=quad*4+reg.

template <int NC, bool CVT>
__global__ __launch_bounds__(256) void k_mfma(const void* __restrict__ Av, const unsigned short* __restrict__ Wtg,
                                              const float* __restrict__ dinv, unsigned short* __restrict__ Y, int M) {
    constexpr int K = 128;
    constexpr int NT = NC / 16;
    constexpr int NU = NC / 32;
    __shared__ unsigned short Wt[NC][136];
    __shared__ unsigned short Ost[4][16][NC + 8];
    int t = threadIdx.x;
    for (int idx = t; idx < NC * 16; idx += 256) {
        int nrow = idx >> 4, chunk = idx & 15;
        *(uint4*)&Wt[nrow][chunk * 8] = *(const uint4*)(Wtg + nrow * K + chunk * 8);
    }
    __syncthreads();
    int lane = t & 63, wid = t >> 6;
    int col = lane & 15, quad = lane >> 4;
    int nstrips = M / 16;
    int stride = gridDim.x * 4;
    int s = blockIdx.x * 4 + wid;
    if (s >= nstrips) return;

    auto loadA = [&](int strip, short8 af[4]) {
        int row0 = strip * 16;
        if (CVT) {
            const float* Af = (const float*)Av + (size_t)(row0 + col) * K + quad * 8;
            #pragma unroll
            for (int ks = 0; ks < 4; ks++) {
                float4 f0 = *(const float4*)(Af + ks * 32);
                float4 f1 = *(const float4*)(Af + ks * 32 + 4);
                short8 v;
                v[0] = (short)f2bf(f0.x); v[1] = (short)f2bf(f0.y); v[2] = (short)f2bf(f0.z); v[3] = (short)f2bf(f0.w);
                v[4] = (short)f2bf(f1.x); v[5] = (short)f2bf(f1.y); v[6] = (short)f2bf(f1.z); v[7] = (short)f2bf(f1.w);
                af[ks] = v;
            }
        } else {
            const unsigned short* Ab = (const unsigned short*)Av + (size_t)(row0 + col) * K + quad * 8;
            #pragma unroll
            for (int ks = 0; ks < 4; ks++) af[ks] = *(const short8*)(Ab + ks * 32);
        }
    };

    short8 cur[4];
    loadA(s, cur);
    while (true) {
        int snext = s + stride;
        bool has = (snext < nstrips);
        short8 nxt[4];
        if (has) loadA(snext, nxt);

        floatx4 acc[NT];
        #pragma unroll
        for (int i = 0; i < NT; i++) acc[i] = (floatx4){0.f, 0.f, 0.f, 0.f};
        #pragma unroll
        for (int ks = 0; ks < 4; ks++) {
            #pragma unroll
            for (int nt = 0; nt < NT; nt++) {
                short8 bfrag = *(const short8*)&Wt[nt * 16 + col][ks * 32 + quad * 8];
                acc[nt] = __builtin_amdgcn_mfma_f32_16x16x32_bf16(cur[ks], bfrag, acc[nt], 0, 0, 0);
            }
        }
        int row0 = s * 16;
        #pragma unroll
        for (int r = 0; r < 4; r++) {
            float dv = dinv[row0 + quad * 4 + r];
            #pragma unroll
            for (int nt = 0; nt < NT; nt++)
                Ost[wid][quad * 4 + r][nt * 16 + col] = f2bf(acc[nt][r] * dv);
        }
        #pragma unroll
        for (int i = 0; i < NU; i++) {
            int idx = i * 64 + lane;
            int rr = (NC == 128) ? (idx >> 4) : (idx >> 3);
            int cc = (NC == 128) ? (idx & 15) : (idx & 7);
            ((uint4*)&Y[(size_t)(row0 + rr) * NC])[cc] = *(uint4*)&Ost[wid][rr][cc * 8];
        }
        if (!has) break;
        s = snext;
        #pragma unroll
        for (int ks = 0; ks < 4; ks++) cur[ks] = nxt[ks];
    }
}

// ---------------- gather + epilogue (bf16 rows), x4 unroll ----------------

__device__ __forceinline__ void acc8(float* a, uint4 v) {
    a[0] += bflo(v.x); a[1] += bfhi(v.x);
    a[2] += bflo(v.y); a[3] += bfhi(v.y);
    a[4] += bflo(v.z); a[5] += bfhi(v.z);
    a[6] += bflo(v.w); a[7] += bfhi(v.w);
}

// 128 ch bf16, split by channel-half (one 128B L2 line per half):
// work item = (node, half); half = blockIdx&1 so HW's blk%8 XCD round-robin pins
// each half to a fixed XCD parity class -> per-XCD L2 only fetches half of each row.
// 8 threads/item, 8 ch (one uint4) per thread, 32 items/block.
__global__ __launch_bounds__(256) void k_gather_relu_bf(const uint4* __restrict__ y, const int* __restrict__ csr,
                                                        const int* __restrict__ row_ptr, const float* __restrict__ dinv,
                                                        const float* __restrict__ bias, uint4* __restrict__ h, int n) {
    int half = blockIdx.x & 1;
    int node = (blockIdx.x >> 1) * 32 + (threadIdx.x >> 3);
    int c = (threadIdx.x & 7) + half * 8;   // uint4 index within the 16-uint4 row
    if (node >= n) return;
    int s0 = row_ptr[node], s1 = row_ptr[node + 1];
    float a[8] = {};
    acc8(a, y[(size_t)node * 16 + c]);       // self loop
    int p = s0;
    for (; p + 4 <= s1; p += 4) {
        int i0 = csr[p], i1 = csr[p + 1], i2 = csr[p + 2], i3 = csr[p + 3];
        uint4 v0 = y[(size_t)i0 * 16 + c];
        uint4 v1 = y[(size_t)i1 * 16 + c];
        uint4 v2 = y[(size_t)i2 * 16 + c];
        uint4 v3 = y[(size_t)i3 * 16 + c];
        acc8(a, v0); acc8(a, v1); acc8(a, v2); acc8(a, v3);
    }
    for (; p < s1; p++) acc8(a, y[(size_t)csr[p] * 16 + c]);
    float s = dinv[node];
    float4 b0 = ((const float4*)bias)[c * 2];
    float4 b1 = ((const float4*)bias)[c * 2 + 1];
    float r0 = fmaxf(s * a[0] + b0.x, 0.f), r1 = fmaxf(s * a[1] + b0.y, 0.f);
    float r2 = fmaxf(s * a[2] + b0.z, 0.f), r3 = fmaxf(s * a[3] + b0.w, 0.f);
    float r4 = fmaxf(s * a[4] + b1.x, 0.f), r5 = fmaxf(s * a[5] + b1.y, 0.f);
    float r6 = fmaxf(s * a[6] + b1.z, 0.f), r7 = fmaxf(s * a[7] + b1.w, 0.f);
    uint4 o;
    o.x = ((unsigned)f2bf(r1) << 16) | f2bf(r0);
    o.y = ((unsigned)f2bf(r3) << 16) | f2bf(r2);
    o.z = ((unsigned)f2bf(r5) << 16) | f2bf(r4);
    o.w = ((unsigned)f2bf(r7) << 16) | f2bf(r6);
    h[(size_t)node * 16 + c] = o;
}

// 64 ch bf16 + log-softmax: 8 threads/node, 8 ch per thread, 32 nodes/block. fp32 output.
// (no channel split: log-softmax needs the full row reduction, and 128B row = 1 line already)
__global__ __launch_bounds__(256) void k_gather_lsm_bf(const uint4* __restrict__ y, const int* __restrict__ csr,
                                                       const int* __restrict__ row_ptr, const float* __restrict__ dinv,
                                                       const float* __restrict__ bias, float4* __restrict__ out4, int n) {
    int node = blockIdx.x * 32 + (threadIdx.x >> 3);
    int c = threadIdx.x & 7;
    if (node >= n) return;
    int s0 = row_ptr[node], s1 = row_ptr[node + 1];
    float a[8] = {};
    acc8(a, y[(size_t)node * 8 + c]);
    int p = s0;
    for (; p + 4 <= s1; p += 4) {
        int i0 = csr[p], i1 = csr[p + 1], i2 = csr[p + 2], i3 = csr[p + 3];
        uint4 v0 = y[(size_t)i0 * 8 + c];
        uint4 v1 = y[(size_t)i1 * 8 + c];
        uint4 v2 = y[(size_t)i2 * 8 + c];
        uint4 v3 = y[(size_t)i3 * 8 + c];
        acc8(a, v0); acc8(a, v1); acc8(a, v2); acc8(a, v3);
    }
    for (; p < s1; p++) acc8(a, y[(size_t)csr[p] * 8 + c]);
    float s = dinv[node];
    float4 b0 = ((const float4*)bias)[c * 2];
    float4 b1 = ((const float4*)bias)[c * 2 + 1];
    float v[8];
    v[0] = s * a[0] + b0.x; v[1] = s * a[1] + b0.y; v[2] = s * a[2] + b0.z; v[3] = s * a[3] + b0.w;
    v[4] = s * a[4] + b1.x; v[5] = s * a[5] + b1.y; v[6] = s * a[6] + b1.z; v[7] = s * a[7] + b1.w;
    float m = v[0];
    #pragma unroll
    for (int i = 1; i < 8; i++) m = fmaxf(m, v[i]);
    #pragma unroll
    for (int o = 4; o > 0; o >>= 1) m = fmaxf(m, __shfl_xor(m, o));
    float sum = 0.f;
    #pragma unroll
    for (int i = 0; i < 8; i++) sum += expf(v[i] - m);
    #pragma unroll
    for (int o = 4; o > 0; o >>= 1) sum += __shfl_xor(sum, o);
    float lse = m + logf(sum);
    out4[(size_t)node * 16 + c * 2]     = make_float4(v[0] - lse, v[1] - lse, v[2] - lse, v[3] - lse);
    out4[(size_t)node * 16 + c * 2 + 1] = make_float4(v[4] - lse, v[5] - lse, v[6] - lse, v[7] - lse);
}

// ---------------- launch ----------------

extern "C" void kernel_launch(void* const* d_in, const int* in_sizes, int n_in,
                              void* d_out, int out_size, void* d_ws, size_t ws_size,
                              hipStream_t stream) {
    const float* x  = (const float*)d_in[0];
    const int*   ei = (const int*)d_in[1];
    const float* W1 = (const float*)d_in[2];
    const float* b1 = (const float*)d_in[3];
    const float* W2 = (const float*)d_in[4];
    const float* b2 = (const float*)d_in[5];
    const float* W3 = (const float*)d_in[6];
    const float* b3 = (const float*)d_in[7];
    float* out = (float*)d_out;

    const int N = NN, E = NE;

    char* ws = (char*)d_ws;
    size_t off = 0;
    auto alloc = [&](size_t bytes) -> void* {
        void* p = ws + off;
        off += bytes;
        off = (off + 255) & ~(size_t)255;
        return p;
    };
    int*            row_ptr = (int*)alloc((size_t)(N + 1) * 4);
    float*          dinvv   = (float*)alloc((size_t)N * 4);
    int*            bcur    = (int*)alloc(512 * 4);
    int*            bbuf    = (int*)alloc((size_t)NBUK * BCAP * 4);
    int*            csr     = (int*)alloc((size_t)E * 4);
    unsigned short* wt1     = (unsigned short*)alloc(128 * 128 * 2);
    unsigned short* wt2     = (unsigned short*)alloc(128 * 128 * 2);
    unsigned short* wt3     = (unsigned short*)alloc(64 * 128 * 2);
    unsigned short* yb      = (unsigned short*)alloc((size_t)N * 128 * 2);
    unsigned short* hb      = (unsigned short*)alloc((size_t)N * 128 * 2);
    (void)ws_size; (void)in_sizes; (void)n_in; (void)out_size;

    const int* srcp = ei;
    const int* dstp = ei + E;

    k_wprep_all<<<160, 256, 0, stream>>>(W1, W2, W3, wt1, wt2, wt3, bcur);
    k_bucket<<<(E + 4095) / 4096, 256, 0, stream>>>((const int4*)srcp, (const int4*)dstp, bcur, bbuf, E);
    k_build<<<NBUK, 256, 0, stream>>>(bcur, bbuf, row_ptr, csr, dinvv, N, E);

    // Layer 1 (fp32 x converted in-register)
    k_mfma<128, true><<<768, 256, 0, stream>>>(x, wt1, dinvv, yb, N);
    k_gather_relu_bf<<<(N / 32) * 2, 256, 0, stream>>>((const uint4*)yb, csr, row_ptr, dinvv, b1, (uint4*)hb, N);
    // Layer 2
    k_mfma<128, false><<<768, 256, 0, stream>>>(hb, wt2, dinvv, yb, N);
    k_gather_relu_bf<<<(N / 32) * 2, 256, 0, stream>>>((const uint4*)yb, csr, row_ptr, dinvv, b2, (uint4*)hb, N);
    // Layer 3 (128 -> 64) + log-softmax
    k_mfma<64, false><<<768, 256, 0, stream>>>(hb, wt3, dinvv, yb, N);
    k_gather_lsm_bf<<<N / 32, 256, 0, stream>>>((const uint4*)yb, csr, row_ptr, dinvv, b3, (float4*)out, N);
}